// Round 4
// baseline (507.273 us; speedup 1.0000x reference)
//
#include <hip/hip_runtime.h>
#include <hip/hip_cooperative_groups.h>
#include <hip/hip_fp16.h>
#include <math.h>

namespace cg = cooperative_groups;

#define Bv   16
#define Nv   256
#define Dv   512
#define Hv   8
#define MNv  4096          // B*N tokens

typedef __attribute__((ext_vector_type(8))) short bf16x8;
typedef __attribute__((ext_vector_type(4))) float f32x4;
typedef __fp16 fp16x8 __attribute__((ext_vector_type(8)));
typedef __fp16 fp16x2 __attribute__((ext_vector_type(2)));

__device__ __forceinline__ unsigned short f2bf(float f) {   // RNE
    unsigned u = __float_as_uint(f);
    u = u + 0x7FFFu + ((u >> 16) & 1u);
    return (unsigned short)(u >> 16);
}
__device__ __forceinline__ void gload_lds16(const void* g, void* l) {
    __builtin_amdgcn_global_load_lds(
        (const __attribute__((address_space(1))) unsigned int*)g,
        (__attribute__((address_space(3))) unsigned int*)l, 16, 0, 0);
}
__device__ __forceinline__ void fast_sincos(float x, float* s, float* c) {
    const float rev = x * 0.15915494309189535f;   // v_sin takes revolutions
    const float fr  = rev - floorf(rev);
    *s = __builtin_amdgcn_sinf(fr);
    *c = __builtin_amdgcn_cosf(fr);
}
__device__ __forceinline__ float fast_log(float x) {
    return __builtin_amdgcn_logf(x) * 0.6931471805599453f;
}
__device__ __forceinline__ float fast_exp(float x) {
    return __builtin_amdgcn_exp2f(x * 1.4426950408889634f);
}

// ---------------------------------------------------------------------------
// Single cooperative kernel: 512 blocks x 256 threads, 72 KB LDS
// (exactly 2 blocks/CU co-resident on 256 CUs).
// Phase 1: geo-bias (8 (b,q) units/block) + input conv (12 units/block)
//          + weight transpose (blocks 0..255).
// Phase 2: qkv GEMM, 768 128x64 tiles (block bid; blocks <256 take +512).
// Phase 3: attention, 512 blocks 1:1.
// Phase 4: out GEMM, 512 64x64 tiles 1:1.
// ---------------------------------------------------------------------------
__global__ __launch_bounds__(256, 2) void fused_kernel(
    const float* __restrict__ box, const int* __restrict__ mask,
    const float* __restrict__ WGw, const float* __restrict__ WGb,
    const float* __restrict__ xq, const float* __restrict__ xk,
    const float* __restrict__ xv,
    const float* __restrict__ Wq, const float* __restrict__ Wk,
    const float* __restrict__ Wv, const float* __restrict__ Wo,
    const float* __restrict__ bq, const float* __restrict__ bk,
    const float* __restrict__ bv, const float* __restrict__ bo,
    unsigned short* __restrict__ Ab, unsigned short* __restrict__ Wt,
    float* __restrict__ bst, __half* __restrict__ LB,
    unsigned short* __restrict__ Qb2, unsigned short* __restrict__ Kb2,
    unsigned short* __restrict__ Vt2, unsigned short* __restrict__ CTXb,
    float* __restrict__ out)
{
    cg::grid_group grid = cg::this_grid();
    __shared__ __align__(16) unsigned short smem[36864];   // 72 KB, phase-aliased

    const int bid = blockIdx.x;
    const int t = threadIdx.x;
    const int w = t >> 6, lane = t & 63;

    // ======================= PHASE 1a: input fp32 -> bf16 ====================
    {
#pragma unroll
        for (int k = 0; k < 12; ++k) {
            const int u = bid * 12 + k;                 // 0..6143
            const int z = u >> 11;
            const int xblk = u & 2047;
            const float* src = (z == 0) ? xq : (z == 1) ? xk : xv;
            const size_t base = (size_t)z * (MNv * Dv);
            const int idx = (xblk * 256 + t) * 4;
            float4 x = *(const float4*)(src + idx);
            ushort4 h4;
            h4.x = f2bf(x.x); h4.y = f2bf(x.y); h4.z = f2bf(x.z); h4.w = f2bf(x.w);
            *(ushort4*)(Ab + base + idx) = h4;
        }
    }

    // ======================= PHASE 1b: geo-bias (8 q-units) ==================
    {
        unsigned short (*Lst)[264] = (unsigned short (*)[264])smem;
        const int n = lane & 15;
        const int quad = lane >> 4;
        const int b = bid >> 5;                // 32 blocks per batch
        const int q0u = (bid & 31) * 8;        // 8 consecutive q per block

        union F16x8 { fp16x8 v; fp16x2 p[4]; };
        F16x8 Bs_, Bc_;
        Bs_.v = (fp16x8){}; Bc_.v = (fp16x8){};
        float bias_n = 0.0f;
        if (n < Hv) {
            bias_n = WGb[n];
#pragma unroll
            for (int jj = 0; jj < 4; ++jj) {
                Bs_.p[jj] = __builtin_amdgcn_cvt_pkrtz(WGw[n * 64 + quad * 8 + 2 * jj],
                                                       WGw[n * 64 + quad * 8 + 2 * jj + 1]);
                Bc_.p[jj] = __builtin_amdgcn_cvt_pkrtz(WGw[n * 64 + 32 + quad * 8 + 2 * jj],
                                                       WGw[n * 64 + 32 + quad * 8 + 2 * jj + 1]);
            }
        }

        const float dimm[8] = {1.0f, 0.42169650342f, 0.17782794100f, 0.07498942093f,
                               0.03162277660f, 0.01333521432f, 0.00562341325f, 0.00237137371f};
        const bool isCtr = (quad < 2);
        const bool isY   = (quad & 1);

        // m-side box math is q-invariant: hoist out of the q-unit loop.
        float cmv[4], smv[4];
        int4 mkv[4];
#pragma unroll
        for (int i = 0; i < 4; ++i) {
            const int m0 = (w * 4 + i) * 16;
            const float4 bm = *(const float4*)(box + (b * Nv + m0 + n) * 4);
            const float cxm = (bm.x + bm.z) * 0.5f;
            const float cym = (bm.y + bm.w) * 0.5f;
            const float wm  = bm.z - bm.x + 1.0f;
            const float hm  = bm.w - bm.y + 1.0f;
            cmv[i] = isY ? cym : cxm;
            smv[i] = isY ? hm : wm;
            mkv[i] = *(const int4*)(mask + b * Nv + m0 + quad * 4);
        }

#pragma unroll 1
        for (int k = 0; k < 8; ++k) {
            const int q = q0u + k;
            const float4 bq_ = *(const float4*)(box + (b * Nv + q) * 4);
            const float cxq = (bq_.x + bq_.z) * 0.5f;
            const float cyq = (bq_.y + bq_.w) * 0.5f;
            const float wq_ = bq_.z - bq_.x + 1.0f;
            const float hq_ = bq_.w - bq_.y + 1.0f;
            const float cq  = isY ? cyq : cxq;
            const float sq2 = isY ? hq_ : wq_;

#pragma unroll
            for (int i = 0; i < 4; ++i) {
                const float top = isCtr ? fabsf(cq - cmv[i]) : sq2;
                const float bot = isCtr ? sq2 : smv[i];
                float r = top * __builtin_amdgcn_rcpf(bot);
                if (isCtr) r = fmaxf(r, 1e-3f);
                const float base = 69.31471805599453f * __builtin_amdgcn_logf(r);

                float sv[8], cv[8];
#pragma unroll
                for (int j = 0; j < 8; ++j)
                    fast_sincos(base * dimm[j], &sv[j], &cv[j]);

                F16x8 As_, Ac_;
#pragma unroll
                for (int jj = 0; jj < 4; ++jj) {
                    As_.p[jj] = __builtin_amdgcn_cvt_pkrtz(sv[2 * jj], sv[2 * jj + 1]);
                    Ac_.p[jj] = __builtin_amdgcn_cvt_pkrtz(cv[2 * jj], cv[2 * jj + 1]);
                }

                f32x4 acc = {};
                acc = __builtin_amdgcn_mfma_f32_16x16x32_f16(As_.v, Bs_.v, acc, 0, 0, 0);
                acc = __builtin_amdgcn_mfma_f32_16x16x32_f16(Ac_.v, Bc_.v, acc, 0, 0, 0);

                if (n < Hv) {
                    const int* mkp = (const int*)&mkv[i];
                    const int pos0 = quad * 64 + (w * 4 + i);
#pragma unroll
                    for (int rr = 0; rr < 4; ++rr) {
                        const float val = fmaxf(acc[rr] + bias_n, 1e-6f);
                        const float lb = fast_log(val) + (mkp[rr] ? 0.0f : -30000.0f);
                        Lst[n][pos0 + rr * 16] = __half_as_ushort(__float2half(lb));
                    }
                }
            }

            __syncthreads();
            const int hh = t >> 5, c = t & 31;
            unsigned short* dst = (unsigned short*)LB +
                                  ((size_t)(b * Hv + hh) * Nv + q) * Nv + c * 8;
            *(int4*)dst = *(const int4*)&Lst[hh][c * 8];
            __syncthreads();   // Lst reused next unit
        }
    }

    // ======================= PHASE 1c: weight transpose ======================
    if (bid < 256) {
        float (*T)[65] = (float (*)[65])smem;           // 16.6 KB, Lst is dead
        const int z = bid >> 6;
        const int rem = bid & 63;
        const int n0 = (rem & 7) * 64, k0 = (rem >> 3) * 64;
        const float* W = (z == 0) ? Wq : (z == 1) ? Wk : (z == 2) ? Wv : Wo;
        const float* b2 = (z == 0) ? bq : (z == 1) ? bk : (z == 2) ? bv : bo;
        const int col = t & 63, rb = t >> 6;
#pragma unroll
        for (int j = 0; j < 16; ++j) {
            const int row = j * 4 + rb;
            T[row][col] = W[(k0 + row) * Dv + n0 + col];
        }
        __syncthreads();
#pragma unroll
        for (int j = 0; j < 16; ++j) {
            const int row = j * 4 + rb;
            Wt[z * (Dv * Dv) + (n0 + row) * Dv + k0 + col] = f2bf(T[col][row]);
        }
        if (rem == 0) {
            bst[z * Dv + t]       = b2[t];
            bst[z * Dv + t + 256] = b2[t + 256];
        }
    }

    __threadfence();
    grid.sync();

    // ======================= PHASE 2: qkv GEMM (768 tiles) ===================
    {
        const int sr = t >> 2;          // src row in 64-row group
        const int sc = (t & 3) * 8;     // src col chunk (halfs)
        const int fr = lane & 15;
        const int fq = lane >> 4;
        const int wm = w & 1, wn = w >> 1;

        // As: smem[0..16383]  = [buf2][kk2][128][32]
        // Bs: smem[16384..24575] = [buf2][kk2][64][32]
        auto qkv_tile = [&](int tile) {
            const int z = tile >> 8;
            const int rem = tile & 255;
            const int n0 = (rem & 7) * 64;
            const int m0 = (rem >> 3) * 128;
            const unsigned short* A = Ab + (size_t)z * (MNv * Dv);
            const unsigned short* Wz = Wt + (size_t)z * (Dv * Dv);
            const float* bias = bst + z * Dv;

            f32x4 acc[4][2] = {};
            auto STAGE = [&](int bu, int k0) {
#pragma unroll
                for (int kk = 0; kk < 2; ++kk) {
#pragma unroll
                    for (int i2 = 0; i2 < 2; ++i2)
                        gload_lds16(A + (size_t)(m0 + i2 * 64 + sr) * Dv + k0 + kk * 32 + sc,
                                    &smem[((bu * 2 + kk) * 128 + i2 * 64 + w * 16) * 32]);
                    gload_lds16(Wz + (size_t)(n0 + sr) * Dv + k0 + kk * 32 + sc,
                                &smem[16384 + ((bu * 2 + kk) * 64 + w * 16) * 32]);
                }
            };

            STAGE(0, 0);
            __syncthreads();
            int cur = 0;
#pragma unroll
            for (int kt = 0; kt < 8; ++kt) {
                if (kt < 7) STAGE(cur ^ 1, (kt + 1) * 64);
                bf16x8 af[2][4], bfr[2][2];
#pragma unroll
                for (int kk = 0; kk < 2; ++kk) {
#pragma unroll
                    for (int mt = 0; mt < 4; ++mt)
                        af[kk][mt] = *(const bf16x8*)
                            &smem[((cur * 2 + kk) * 128 + wm * 64 + mt * 16 + fr) * 32 + fq * 8];
#pragma unroll
                    for (int nt = 0; nt < 2; ++nt)
                        bfr[kk][nt] = *(const bf16x8*)
                            &smem[16384 + ((cur * 2 + kk) * 64 + wn * 32 + nt * 16 + fr) * 32 + fq * 8];
                }
#pragma unroll
                for (int mt = 0; mt < 4; ++mt)
#pragma unroll
                    for (int nt = 0; nt < 2; ++nt) {
                        acc[mt][nt] = __builtin_amdgcn_mfma_f32_16x16x32_bf16(
                            af[0][mt], bfr[0][nt], acc[mt][nt], 0, 0, 0);
                        acc[mt][nt] = __builtin_amdgcn_mfma_f32_16x16x32_bf16(
                            af[1][mt], bfr[1][nt], acc[mt][nt], 0, 0, 0);
                    }
                __syncthreads();
                cur ^= 1;
            }

            const int er = (lane >> 4) * 4;
            const int ec = lane & 15;
            const float scale = (z == 0) ? 0.125f : 1.0f;
#pragma unroll
            for (int nt = 0; nt < 2; ++nt) {
                const int gn = n0 + wn * 32 + nt * 16 + ec;
                const float bv_ = bias[gn];
#pragma unroll
                for (int mt = 0; mt < 4; ++mt) {
                    const int gm = m0 + wm * 64 + mt * 16 + er;
                    if (z == 2) {
                        ushort4 o;
                        o.x = f2bf(acc[mt][nt][0] + bv_);
                        o.y = f2bf(acc[mt][nt][1] + bv_);
                        o.z = f2bf(acc[mt][nt][2] + bv_);
                        o.w = f2bf(acc[mt][nt][3] + bv_);
                        *(ushort4*)(Vt2 + ((size_t)(gm >> 8) * Dv + gn) * Nv + (gm & 255)) = o;
                    } else {
                        unsigned short* cp = ((z == 0) ? Qb2 : Kb2) + (size_t)gm * Dv + gn;
#pragma unroll
                        for (int r = 0; r < 4; ++r)
                            cp[(size_t)r * Dv] = f2bf((acc[mt][nt][r] + bv_) * scale);
                    }
                }
            }
        };

        qkv_tile(bid);
        __syncthreads();
        if (bid < 256) qkv_tile(bid + 512);
    }

    __threadfence();
    grid.sync();

    // ======================= PHASE 3: attention ==============================
    {
        const int qt = bid & 3, h = (bid >> 2) & 7, b = bid >> 5;
        const int q0 = qt * 64;
        const int fr = lane & 15, fq = lane >> 4;

        // LDS partition (all stride-32-half sub-tiles):
        //   [0,8192)      K0 [256][32]   [8192,16384)  K1 [256][32]
        //   [16384,18432) Q0 [64][32]    [18432,20480) Q1 [64][32]
        //   [20480,36864) Vs [8][64][32]
        //   P [64][264] aliases [0,16896) after QK^T.
        unsigned short (*K0)[32] = (unsigned short (*)[32])&smem[0];
        unsigned short (*K1)[32] = (unsigned short (*)[32])&smem[8192];
        unsigned short (*Q0)[32] = (unsigned short (*)[32])&smem[16384];
        unsigned short (*Q1)[32] = (unsigned short (*)[32])&smem[18432];
        unsigned short (*Vs)[32] = (unsigned short (*)[32])&smem[20480];
        unsigned short (*Pb)[264] = (unsigned short (*)[264])&smem[0];

        const int sr = t >> 2;
        const int sc = (t & 3) * 8;

        const int qb = q0 + w * 16 + fq * 4;
        const __half* lbp = LB + ((size_t)(b * Hv + h) * Nv + qb) * Nv + fr * 16;
        int4 lbv[4][2];
#pragma unroll
        for (int r = 0; r < 4; ++r) {
            const int4* p = (const int4*)(lbp + (size_t)r * Nv);
            lbv[r][0] = p[0];
            lbv[r][1] = p[1];
        }

#pragma unroll
        for (int i = 0; i < 4; ++i) {          // K
            gload_lds16(Kb2 + (size_t)(b * Nv + i * 64 + sr) * Dv + h * 64 + sc,
                        &K0[i * 64 + w * 16][0]);
            gload_lds16(Kb2 + (size_t)(b * Nv + i * 64 + sr) * Dv + h * 64 + 32 + sc,
                        &K1[i * 64 + w * 16][0]);
        }
        gload_lds16(Qb2 + (size_t)(b * Nv + q0 + sr) * Dv + h * 64 + sc, &Q0[w * 16][0]);
        gload_lds16(Qb2 + (size_t)(b * Nv + q0 + sr) * Dv + h * 64 + 32 + sc, &Q1[w * 16][0]);
#pragma unroll
        for (int kt = 0; kt < 8; ++kt)         // V^T
            gload_lds16(Vt2 + (size_t)b * (Dv * Nv) + (h * 64 + sr) * Nv + kt * 32 + sc,
                        &Vs[kt * 64 + w * 16][0]);

        f32x4 acc[16];
#pragma unroll
        for (int r = 0; r < 4; ++r) {
            const __half* hs0 = (const __half*)&lbv[r][0];
            const __half* hs1 = (const __half*)&lbv[r][1];
#pragma unroll
            for (int nt = 0; nt < 8; ++nt) acc[nt][r]     = __half2float(hs0[nt]);
#pragma unroll
            for (int nt = 0; nt < 8; ++nt) acc[nt + 8][r] = __half2float(hs1[nt]);
        }

        __syncthreads();

        const bf16x8 aq0 = *(const bf16x8*)&Q0[w * 16 + fr][fq * 8];
        const bf16x8 aq1 = *(const bf16x8*)&Q1[w * 16 + fr][fq * 8];
#pragma unroll
        for (int nt = 0; nt < 16; ++nt) {
            const bf16x8 bk0 = *(const bf16x8*)&K0[nt * 16 + fr][fq * 8];
            const bf16x8 bk1 = *(const bf16x8*)&K1[nt * 16 + fr][fq * 8];
            acc[nt] = __builtin_amdgcn_mfma_f32_16x16x32_bf16(aq0, bk0, acc[nt], 0, 0, 0);
            acc[nt] = __builtin_amdgcn_mfma_f32_16x16x32_bf16(aq1, bk1, acc[nt], 0, 0, 0);
        }

        float ri[4];
#pragma unroll
        for (int r = 0; r < 4; ++r) {
            float mx = acc[0][r];
#pragma unroll
            for (int nt = 1; nt < 16; ++nt) mx = fmaxf(mx, acc[nt][r]);
            mx = fmaxf(mx, __shfl_xor(mx, 1));
            mx = fmaxf(mx, __shfl_xor(mx, 2));
            mx = fmaxf(mx, __shfl_xor(mx, 4));
            mx = fmaxf(mx, __shfl_xor(mx, 8));
            float s = 0.0f;
#pragma unroll
            for (int nt = 0; nt < 16; ++nt) {
                const float e = fast_exp(acc[nt][r] - mx);
                acc[nt][r] = e;
                s += e;
            }
            s += __shfl_xor(s, 1);
            s += __shfl_xor(s, 2);
            s += __shfl_xor(s, 4);
            s += __shfl_xor(s, 8);
            ri[r] = __builtin_amdgcn_rcpf(s);
        }

        __syncthreads();

#pragma unroll
        for (int nt = 0; nt < 16; ++nt)
#pragma unroll
            for (int r = 0; r < 4; ++r)
                Pb[w * 16 + fq * 4 + r][nt * 16 + fr] = f2bf(acc[nt][r] * ri[r]);

        f32x4 o[4] = {};
#pragma unroll
        for (int kt = 0; kt < 8; ++kt) {
            const bf16x8 ap = *(const bf16x8*)&Pb[w * 16 + fr][kt * 32 + fq * 8];
#pragma unroll
            for (int nt2 = 0; nt2 < 4; ++nt2) {
                const bf16x8 bv_ = *(const bf16x8*)&Vs[kt * 64 + nt2 * 16 + fr][fq * 8];
                o[nt2] = __builtin_amdgcn_mfma_f32_16x16x32_bf16(ap, bv_, o[nt2], 0, 0, 0);
            }
        }

#pragma unroll
        for (int nt2 = 0; nt2 < 4; ++nt2)
#pragma unroll
            for (int r = 0; r < 4; ++r)
                CTXb[(size_t)(b * Nv + qb + r) * Dv + h * 64 + nt2 * 16 + fr] =
                    f2bf(o[nt2][r]);

        __syncthreads();   // LDS free before phase 4
    }

    __threadfence();
    grid.sync();

    // ======================= PHASE 4: out GEMM (512 64x64 tiles) =============
    {
        const int n0 = (bid & 7) * 64;
        const int m0 = (bid >> 3) * 64;
        const int sr = t >> 2;
        const int sc = (t & 3) * 8;
        const int fr = lane & 15;
        const int fq = lane >> 4;
        const unsigned short* Wzo = Wt + 3 * (Dv * Dv);
        const float* biaso = bst + 3 * Dv;

        // As: smem[0..8191] = [buf2][kk2][64][32]; Bs: smem[8192..16383] same
        f32x4 acc[4] = {};
        auto STG = [&](int bu, int k0) {
#pragma unroll
            for (int kk = 0; kk < 2; ++kk) {
                gload_lds16(CTXb + (size_t)(m0 + sr) * Dv + k0 + kk * 32 + sc,
                            &smem[((bu * 2 + kk) * 64 + w * 16) * 32]);
                gload_lds16(Wzo + (size_t)(n0 + sr) * Dv + k0 + kk * 32 + sc,
                            &smem[8192 + ((bu * 2 + kk) * 64 + w * 16) * 32]);
            }
        };

        STG(0, 0);
        __syncthreads();
        int cur = 0;
#pragma unroll
        for (int kt = 0; kt < 8; ++kt) {
            if (kt < 7) STG(cur ^ 1, (kt + 1) * 64);
            bf16x8 af[2];
            bf16x8 bfr[2][4];
#pragma unroll
            for (int kk = 0; kk < 2; ++kk) {
                af[kk] = *(const bf16x8*)
                    &smem[((cur * 2 + kk) * 64 + w * 16 + fr) * 32 + fq * 8];
#pragma unroll
                for (int nt = 0; nt < 4; ++nt)
                    bfr[kk][nt] = *(const bf16x8*)
                        &smem[8192 + ((cur * 2 + kk) * 64 + nt * 16 + fr) * 32 + fq * 8];
            }
#pragma unroll
            for (int nt = 0; nt < 4; ++nt) {
                acc[nt] = __builtin_amdgcn_mfma_f32_16x16x32_bf16(
                    af[0], bfr[0][nt], acc[nt], 0, 0, 0);
                acc[nt] = __builtin_amdgcn_mfma_f32_16x16x32_bf16(
                    af[1], bfr[1][nt], acc[nt], 0, 0, 0);
            }
            __syncthreads();
            cur ^= 1;
        }

        const int er = (lane >> 4) * 4;
        const int ec = lane & 15;
#pragma unroll
        for (int nt = 0; nt < 4; ++nt) {
            const int gn = n0 + nt * 16 + ec;
            const float bv_ = biaso[gn];
            float* cp = out + (size_t)(m0 + w * 16 + er) * Dv + gn;
#pragma unroll
            for (int r = 0; r < 4; ++r)
                cp[(size_t)r * Dv] = acc[nt][r] + bv_;
        }
    }
}

// ---------------------------------------------------------------------------
extern "C" void kernel_launch(void* const* d_in, const int* in_sizes, int n_in,
                              void* d_out, int out_size, void* d_ws, size_t ws_size,
                              hipStream_t stream) {
    (void)in_sizes; (void)n_in; (void)out_size; (void)ws_size;

    const float* inq  = (const float*)d_in[0];
    const float* ink  = (const float*)d_in[1];
    const float* inv  = (const float*)d_in[2];
    const float* box  = (const float*)d_in[3];
    const int*   mask = (const int*)d_in[4];
    const float* Wq   = (const float*)d_in[5];
    const float* bq   = (const float*)d_in[6];
    const float* Wk   = (const float*)d_in[7];
    const float* bk   = (const float*)d_in[8];
    const float* Wv   = (const float*)d_in[9];
    const float* bv   = (const float*)d_in[10];
    const float* Wo   = (const float*)d_in[11];
    const float* bo   = (const float*)d_in[12];
    const float* WGw  = (const float*)d_in[13];
    const float* WGb  = (const float*)d_in[14];

    char* W = (char*)d_ws;
    const size_t MB = 1048576;
    unsigned short* Qb2  = (unsigned short*)(W + 0);        // 4 MB bf16, pre-scaled 1/8
    unsigned short* Kb2  = (unsigned short*)(W + 4 * MB);   // 4 MB bf16
    unsigned short* Vt2  = (unsigned short*)(W + 8 * MB);   // 4 MB bf16 [b][d][m]
    unsigned short* Wt   = (unsigned short*)(W + 12 * MB);  // 2 MB
    float*          bst  = (float*)(W + 14 * MB);           // 8 KB
    unsigned short* CTXb = (unsigned short*)(W + 15 * MB);  // 4 MB
    unsigned short* Ab   = (unsigned short*)(W + 20 * MB);  // 12 MB
    __half*         LB   = (__half*)(W + 32 * MB);          // 16.8 MB

    float* out = (float*)d_out;

    void* args[] = {
        (void*)&box, (void*)&mask, (void*)&WGw, (void*)&WGb,
        (void*)&inq, (void*)&ink, (void*)&inv,
        (void*)&Wq, (void*)&Wk, (void*)&Wv, (void*)&Wo,
        (void*)&bq, (void*)&bk, (void*)&bv, (void*)&bo,
        (void*)&Ab, (void*)&Wt, (void*)&bst, (void*)&LB,
        (void*)&Qb2, (void*)&Kb2, (void*)&Vt2, (void*)&CTXb, (void*)&out
    };
    hipLaunchCooperativeKernel(reinterpret_cast<void*>(fused_kernel),
                               dim3(512), dim3(256), args, 0, stream);
}

// Round 6
// 155.353 us; speedup vs baseline: 3.2653x; 3.2653x over previous
//
#include <hip/hip_runtime.h>
#include <hip/hip_fp16.h>
#include <math.h>

#define Bv   16
#define Nv   256
#define Dv   512
#define Hv   8
#define MNv  4096          // B*N tokens

typedef __attribute__((ext_vector_type(8))) short bf16x8;
typedef __attribute__((ext_vector_type(4))) float f32x4;
typedef __fp16 fp16x8 __attribute__((ext_vector_type(8)));
typedef __fp16 fp16x2 __attribute__((ext_vector_type(2)));

__device__ __forceinline__ unsigned short f2bf(float f) {   // RNE
    unsigned u = __float_as_uint(f);
    u = u + 0x7FFFu + ((u >> 16) & 1u);
    return (unsigned short)(u >> 16);
}
__device__ __forceinline__ void gload_lds16(const void* g, void* l) {
    __builtin_amdgcn_global_load_lds(
        (const __attribute__((address_space(1))) unsigned int*)g,
        (__attribute__((address_space(3))) unsigned int*)l, 16, 0, 0);
}

// Raw HW transcendentals.
__device__ __forceinline__ void fast_sincos(float x, float* s, float* c) {
    const float rev = x * 0.15915494309189535f;   // v_sin takes revolutions
    const float fr  = rev - floorf(rev);
    *s = __builtin_amdgcn_sinf(fr);
    *c = __builtin_amdgcn_cosf(fr);
}
__device__ __forceinline__ float fast_log(float x) {
    return __builtin_amdgcn_logf(x) * 0.6931471805599453f;
}
__device__ __forceinline__ float fast_exp(float x) {
    return __builtin_amdgcn_exp2f(x * 1.4426950408889634f);
}

// ---------------------------------------------------------------------------
// MEGA-1: geo-bias (blocks 0..4095) + fp32->bf16 input conv (4096..7167,
// 32 B/thread) + weight transpose conv (7168..7423), one launch.
// ---------------------------------------------------------------------------
__global__ __launch_bounds__(256) void mega1_kernel(
    const float* __restrict__ box, const int* __restrict__ mask,
    const float* __restrict__ WGw, const float* __restrict__ WGb,
    __half* __restrict__ LB,
    const float* __restrict__ xq, const float* __restrict__ xk,
    const float* __restrict__ xv, unsigned short* __restrict__ Ab,
    const float* __restrict__ Wq, const float* __restrict__ Wk,
    const float* __restrict__ Wv, const float* __restrict__ Wo,
    const float* __restrict__ bq, const float* __restrict__ bk,
    const float* __restrict__ bv, const float* __restrict__ bo,
    unsigned short* __restrict__ Wt, float* __restrict__ biasStack)
{
    __shared__ __align__(16) char smraw[64 * 65 * 4];   // union: geo Lst / conv_w T
    const int bid = blockIdx.x;
    const int t = threadIdx.x;

    if (bid < 4096) {
        // ================= geo-bias =================
        unsigned short (*Lst)[264] = (unsigned short (*)[264])smraw;
        const int q = bid & 255;
        const int b = bid >> 8;
        const int w = t >> 6, lane = t & 63;
        const int n = lane & 15;
        const int quad = lane >> 4;

        const float4 bq_ = *(const float4*)(box + (b * Nv + q) * 4);
        const float cxq = (bq_.x + bq_.z) * 0.5f;
        const float cyq = (bq_.y + bq_.w) * 0.5f;
        const float wq  = bq_.z - bq_.x + 1.0f;
        const float hq  = bq_.w - bq_.y + 1.0f;

        union F16x8 { fp16x8 v; fp16x2 p[4]; };
        F16x8 Bs_, Bc_;
        Bs_.v = (fp16x8){}; Bc_.v = (fp16x8){};
        float bias_n = 0.0f;
        if (n < Hv) {
            bias_n = WGb[n];
#pragma unroll
            for (int jj = 0; jj < 4; ++jj) {
                Bs_.p[jj] = __builtin_amdgcn_cvt_pkrtz(WGw[n * 64 + quad * 8 + 2 * jj],
                                                       WGw[n * 64 + quad * 8 + 2 * jj + 1]);
                Bc_.p[jj] = __builtin_amdgcn_cvt_pkrtz(WGw[n * 64 + 32 + quad * 8 + 2 * jj],
                                                       WGw[n * 64 + 32 + quad * 8 + 2 * jj + 1]);
            }
        }

        const float dimm[8] = {1.0f, 0.42169650342f, 0.17782794100f, 0.07498942093f,
                               0.03162277660f, 0.01333521432f, 0.00562341325f, 0.00237137371f};
        const bool isCtr = (quad < 2);
        const bool isY   = (quad & 1);
        const float cq  = isY ? cyq : cxq;
        const float sq_ = isY ? hq : wq;

#pragma unroll
        for (int i = 0; i < 4; ++i) {
            const int m0 = (w * 4 + i) * 16;
            const float4 bm = *(const float4*)(box + (b * Nv + m0 + n) * 4);
            const float cxm = (bm.x + bm.z) * 0.5f;
            const float cym = (bm.y + bm.w) * 0.5f;
            const float wm  = bm.z - bm.x + 1.0f;
            const float hm  = bm.w - bm.y + 1.0f;
            const float cm_ = isY ? cym : cxm;
            const float sm_ = isY ? hm : wm;
            const float top = isCtr ? fabsf(cq - cm_) : sq_;
            const float bot = isCtr ? sq_ : sm_;
            float r = top * __builtin_amdgcn_rcpf(bot);
            if (isCtr) r = fmaxf(r, 1e-3f);
            const float base = 69.31471805599453f * __builtin_amdgcn_logf(r);

            float sv[8], cv[8];
#pragma unroll
            for (int j = 0; j < 8; ++j)
                fast_sincos(base * dimm[j], &sv[j], &cv[j]);

            F16x8 As_, Ac_;
#pragma unroll
            for (int jj = 0; jj < 4; ++jj) {
                As_.p[jj] = __builtin_amdgcn_cvt_pkrtz(sv[2 * jj], sv[2 * jj + 1]);
                Ac_.p[jj] = __builtin_amdgcn_cvt_pkrtz(cv[2 * jj], cv[2 * jj + 1]);
            }

            f32x4 acc = {};
            acc = __builtin_amdgcn_mfma_f32_16x16x32_f16(As_.v, Bs_.v, acc, 0, 0, 0);
            acc = __builtin_amdgcn_mfma_f32_16x16x32_f16(Ac_.v, Bc_.v, acc, 0, 0, 0);

            const int mrow = m0 + quad * 4;
            const int4 mk = *(const int4*)(mask + b * Nv + mrow);
            if (n < Hv) {
                const int* mkp = (const int*)&mk;
                const int pos0 = quad * 64 + (w * 4 + i);
#pragma unroll
                for (int rr = 0; rr < 4; ++rr) {
                    const float val = fmaxf(acc[rr] + bias_n, 1e-6f);
                    const float lb = fast_log(val) + (mkp[rr] ? 0.0f : -30000.0f);
                    Lst[n][pos0 + rr * 16] = __half_as_ushort(__float2half(lb));
                }
            }
        }

        __syncthreads();
        const int h = t >> 5, c = t & 31;
        unsigned short* dst = (unsigned short*)LB +
                              ((size_t)(b * Hv + h) * Nv + q) * Nv + c * 8;
        *(int4*)dst = *(const int4*)&Lst[h][c * 8];

    } else if (bid < 7168) {
        // ================= input fp32 -> bf16 (32 B/thread) =================
        const int i = bid - 4096;         // 0..3071
        const int z = i >> 10;            // 0..2
        const int xblk = i & 1023;
        const float* src = (z == 0) ? xq : (z == 1) ? xk : xv;
        const size_t base = (size_t)z * (MNv * Dv);
        const int idx = (xblk * 256 + t) * 8;
#pragma unroll
        for (int j = 0; j < 2; ++j) {
            float4 x = *(const float4*)(src + idx + j * 4);
            ushort4 h4;
            h4.x = f2bf(x.x); h4.y = f2bf(x.y); h4.z = f2bf(x.z); h4.w = f2bf(x.w);
            *(ushort4*)(Ab + base + idx + j * 4) = h4;
        }

    } else {
        // ================= weight transpose (fp32 W[k][n] -> bf16 Wt[n][k]) =====
        float (*T)[65] = (float (*)[65])smraw;
        const int i = bid - 7168;         // 0..255
        const int z = i >> 6;
        const int rem = i & 63;
        const int n0 = (rem & 7) * 64, k0 = (rem >> 3) * 64;
        const float* W = (z == 0) ? Wq : (z == 1) ? Wk : (z == 2) ? Wv : Wo;
        const float* b = (z == 0) ? bq : (z == 1) ? bk : (z == 2) ? bv : bo;
        const int col = t & 63, rb = t >> 6;
#pragma unroll
        for (int j = 0; j < 16; ++j) {
            const int row = j * 4 + rb;
            T[row][col] = W[(k0 + row) * Dv + n0 + col];
        }
        __syncthreads();
#pragma unroll
        for (int j = 0; j < 16; ++j) {
            const int row = j * 4 + rb;
            Wt[z * (Dv * Dv) + (n0 + row) * Dv + k0 + col] = f2bf(T[col][row]);
        }
        if (rem == 0) {
            biasStack[z * Dv + t]       = b[t];
            biasStack[z * Dv + t + 256] = b[t + 256];
        }
    }
}

// ---------------------------------------------------------------------------
// Fused Q/K/V projection GEMM, 128x64 tile, BK=64, double-buffered 2-phase.
// grid (8,32,3) = 768 blocks.
// z=0: Q bf16 scaled 1/8; z=1: K bf16; z=2: V bf16 transposed [b][d][m].
// ---------------------------------------------------------------------------
__global__ __launch_bounds__(256) void qkv_gemm_kernel(
    const unsigned short* __restrict__ Ab, const unsigned short* __restrict__ Wt,
    const float* __restrict__ bst, unsigned short* __restrict__ Qb2,
    unsigned short* __restrict__ Kb2, unsigned short* __restrict__ Vt2)
{
    const int z = blockIdx.z;
    const unsigned short* A = Ab + (size_t)z * (MNv * Dv);
    const unsigned short* Wz = Wt + (size_t)z * (Dv * Dv);
    const float* bias = bst + z * Dv;

    const int n0 = blockIdx.x * 64;
    const int m0 = blockIdx.y * 128;
    const int t = threadIdx.x;
    const int w = t >> 6, lane = t & 63;
    const int wm = w & 1, wn = w >> 1;

    __shared__ __align__(16) unsigned short As[2][2][128][32];  // [buf][kk]
    __shared__ __align__(16) unsigned short Bs[2][2][64][32];

    f32x4 acc[4][2] = {};

    const int sr = t >> 2;          // src row within 64-row group
    const int sc = (t & 3) * 8;     // src col chunk (halfs)
    const int fr = lane & 15;
    const int fq = lane >> 4;

    auto STAGE = [&](int bu, int k0) {
#pragma unroll
        for (int kk = 0; kk < 2; ++kk) {
#pragma unroll
            for (int i = 0; i < 2; ++i)
                gload_lds16(A + (size_t)(m0 + i * 64 + sr) * Dv + k0 + kk * 32 + sc,
                            &As[bu][kk][i * 64 + w * 16][0]);
            gload_lds16(Wz + (size_t)(n0 + sr) * Dv + k0 + kk * 32 + sc,
                        &Bs[bu][kk][w * 16][0]);
        }
    };

    STAGE(0, 0);
    __syncthreads();
    int cur = 0;
#pragma unroll
    for (int kt = 0; kt < 8; ++kt) {
        if (kt < 7) STAGE(cur ^ 1, (kt + 1) * 64);   // prefetch next K-tile

        bf16x8 af[2][4], bfr[2][2];
#pragma unroll
        for (int kk = 0; kk < 2; ++kk) {
#pragma unroll
            for (int mt = 0; mt < 4; ++mt)
                af[kk][mt] = *(const bf16x8*)&As[cur][kk][wm * 64 + mt * 16 + fr][fq * 8];
#pragma unroll
            for (int nt = 0; nt < 2; ++nt)
                bfr[kk][nt] = *(const bf16x8*)&Bs[cur][kk][wn * 32 + nt * 16 + fr][fq * 8];
        }
#pragma unroll
        for (int mt = 0; mt < 4; ++mt)
#pragma unroll
            for (int nt = 0; nt < 2; ++nt) {
                acc[mt][nt] = __builtin_amdgcn_mfma_f32_16x16x32_bf16(
                    af[0][mt], bfr[0][nt], acc[mt][nt], 0, 0, 0);
                acc[mt][nt] = __builtin_amdgcn_mfma_f32_16x16x32_bf16(
                    af[1][mt], bfr[1][nt], acc[mt][nt], 0, 0, 0);
            }
        __syncthreads();   // next tile staged (vmcnt0) + cur reads done
        cur ^= 1;
    }

    const int er = (lane >> 4) * 4;
    const int ec = lane & 15;
    const float scale = (z == 0) ? 0.125f : 1.0f;
#pragma unroll
    for (int nt = 0; nt < 2; ++nt) {
        const int gn = n0 + wn * 32 + nt * 16 + ec;
        const float bv_ = bias[gn];
#pragma unroll
        for (int mt = 0; mt < 4; ++mt) {
            const int gm = m0 + wm * 64 + mt * 16 + er;
            if (z == 2) {
                ushort4 o;
                o.x = f2bf(acc[mt][nt][0] + bv_);
                o.y = f2bf(acc[mt][nt][1] + bv_);
                o.z = f2bf(acc[mt][nt][2] + bv_);
                o.w = f2bf(acc[mt][nt][3] + bv_);
                *(ushort4*)(Vt2 + ((size_t)(gm >> 8) * Dv + gn) * Nv + (gm & 255)) = o;
            } else {
                unsigned short* cp = ((z == 0) ? Qb2 : Kb2) + (size_t)gm * Dv + gn;
#pragma unroll
                for (int r = 0; r < 4; ++r)
                    cp[(size_t)r * Dv] = f2bf((acc[mt][nt][r] + bv_) * scale);
            }
        }
    }
}

// ---------------------------------------------------------------------------
// Output GEMM: out[4096][512] = CTXb @ Wo^T + bias, fp32.  64x64 tile,
// BK=64 double-buffered, grid (8,64) = 512 blocks (2 blocks/CU).
// ---------------------------------------------------------------------------
__global__ __launch_bounds__(256) void out_gemm_kernel(
    const unsigned short* __restrict__ A, const unsigned short* __restrict__ Wz,
    const float* __restrict__ bias, float* __restrict__ C)
{
    const int n0 = blockIdx.x * 64;
    const int m0 = blockIdx.y * 64;
    const int t = threadIdx.x;
    const int w = t >> 6, lane = t & 63;

    __shared__ __align__(16) unsigned short As2[2][2][64][32];
    __shared__ __align__(16) unsigned short Bs2[2][2][64][32];

    f32x4 acc[4] = {};

    const int sr = t >> 2;
    const int sc = (t & 3) * 8;
    const int fr = lane & 15;
    const int fq = lane >> 4;

    auto STG = [&](int bu, int k0) {
#pragma unroll
        for (int kk = 0; kk < 2; ++kk) {
            gload_lds16(A + (size_t)(m0 + sr) * Dv + k0 + kk * 32 + sc,
                        &As2[bu][kk][w * 16][0]);
            gload_lds16(Wz + (size_t)(n0 + sr) * Dv + k0 + kk * 32 + sc,
                        &Bs2[bu][kk][w * 16][0]);
        }
    };

    STG(0, 0);
    __syncthreads();
    int cur = 0;
#pragma unroll
    for (int kt = 0; kt < 8; ++kt) {
        if (kt < 7) STG(cur ^ 1, (kt + 1) * 64);

        bf16x8 af[2];
        bf16x8 bfr[2][4];
#pragma unroll
        for (int kk = 0; kk < 2; ++kk) {
            af[kk] = *(const bf16x8*)&As2[cur][kk][w * 16 + fr][fq * 8];
#pragma unroll
            for (int nt = 0; nt < 4; ++nt)
                bfr[kk][nt] = *(const bf16x8*)&Bs2[cur][kk][nt * 16 + fr][fq * 8];
        }
#pragma unroll
        for (int nt = 0; nt < 4; ++nt) {
            acc[nt] = __builtin_amdgcn_mfma_f32_16x16x32_bf16(
                af[0], bfr[0][nt], acc[nt], 0, 0, 0);
            acc[nt] = __builtin_amdgcn_mfma_f32_16x16x32_bf16(
                af[1], bfr[1][nt], acc[nt], 0, 0, 0);
        }
        __syncthreads();
        cur ^= 1;
    }

    const int er = (lane >> 4) * 4;
    const int ec = lane & 15;
#pragma unroll
    for (int nt = 0; nt < 4; ++nt) {
        const int gn = n0 + nt * 16 + ec;
        const float bv_ = bias[gn];
        float* cp = C + (size_t)(m0 + w * 16 + er) * Dv + gn;
#pragma unroll
        for (int r = 0; r < 4; ++r)
            cp[(size_t)r * Dv] = acc[nt][r] + bv_;
    }
}

// ---------------------------------------------------------------------------
// attn3 (MFMA): block=(64q, h, b), 4 waves; wave owns 16 q rows.
// Staging via async global_load_lds into sub-tiled [rows][32] LDS buffers.
// LB (permuted) preloaded as MFMA C accumulator; Q pre-scaled 1/8.
// Softmax in registers (HW v_exp/v_rcp); P -> LDS (aliasing dead K/Q region).
// ---------------------------------------------------------------------------
__global__ __launch_bounds__(256) void attn3_kernel(
    const unsigned short* __restrict__ Qb2, const unsigned short* __restrict__ Kb2,
    const unsigned short* __restrict__ Vt2, const __half* __restrict__ LB,
    unsigned short* __restrict__ CTXb)
{
    const int qt = blockIdx.x, h = blockIdx.y, b = blockIdx.z;
    const int q0 = qt * 64;
    const int t = threadIdx.x, w = t >> 6, lane = t & 63;
    const int fr = lane & 15, fq = lane >> 4;

    // 72 KB LDS, manually partitioned (all stride-32-half sub-tiles):
    //   [0,8192)      K0  [256][32]   (d 0..31 of head)
    //   [8192,16384)  K1  [256][32]   (d 32..63)
    //   [16384,18432) Q0  [64][32]
    //   [18432,20480) Q1  [64][32]
    //   [20480,36864) Vs  [8][64][32] (m-chunk kt, d-row, m within chunk)
    //   P [64][264] aliases [0,16896) — K/Q dead after QK^T reads.
    __shared__ __align__(16) unsigned short smem[36864];
    unsigned short (*K0)[32] = (unsigned short (*)[32])&smem[0];
    unsigned short (*K1)[32] = (unsigned short (*)[32])&smem[8192];
    unsigned short (*Q0)[32] = (unsigned short (*)[32])&smem[16384];
    unsigned short (*Q1)[32] = (unsigned short (*)[32])&smem[18432];
    unsigned short (*Vs)[32] = (unsigned short (*)[32])&smem[20480];
    unsigned short (*Pb)[264] = (unsigned short (*)[264])&smem[0];

    const int sr = t >> 2;          // 0..63 row within a 64-row staging group
    const int sc = (t & 3) * 8;     // col chunk in halfs

    // ---- LB bias loads FIRST (plain loads to regs, ahead of gload queue) ----
    const int qb = q0 + w * 16 + fq * 4;
    const __half* lbp = LB + ((size_t)(b * Hv + h) * Nv + qb) * Nv + fr * 16;
    int4 lbv[4][2];
#pragma unroll
    for (int r = 0; r < 4; ++r) {
        const int4* p = (const int4*)(lbp + (size_t)r * Nv);
        lbv[r][0] = p[0];
        lbv[r][1] = p[1];
    }

    // ---- async staging: 18 x global_load_lds_dwordx4 ----
#pragma unroll
    for (int i = 0; i < 4; ++i) {          // K: 256 rows x 64 d
        gload_lds16(Kb2 + (size_t)(b * Nv + i * 64 + sr) * Dv + h * 64 + sc,
                    &K0[i * 64 + w * 16][0]);
        gload_lds16(Kb2 + (size_t)(b * Nv + i * 64 + sr) * Dv + h * 64 + 32 + sc,
                    &K1[i * 64 + w * 16][0]);
    }
    gload_lds16(Qb2 + (size_t)(b * Nv + q0 + sr) * Dv + h * 64 + sc,
                &Q0[w * 16][0]);
    gload_lds16(Qb2 + (size_t)(b * Nv + q0 + sr) * Dv + h * 64 + 32 + sc,
                &Q1[w * 16][0]);
#pragma unroll
    for (int kt = 0; kt < 8; ++kt)         // V^T: 64 d-rows x 256 m
        gload_lds16(Vt2 + (size_t)b * (Dv * Nv) + (h * 64 + sr) * Nv + kt * 32 + sc,
                    &Vs[kt * 64 + w * 16][0]);

    // ---- unpack LB into acc (overlaps with staging in flight) ----
    f32x4 acc[16];
#pragma unroll
    for (int r = 0; r < 4; ++r) {
        const __half* hs0 = (const __half*)&lbv[r][0];
        const __half* hs1 = (const __half*)&lbv[r][1];
#pragma unroll
        for (int nt = 0; nt < 8; ++nt) acc[nt][r]     = __half2float(hs0[nt]);
#pragma unroll
        for (int nt = 0; nt < 8; ++nt) acc[nt + 8][r] = __half2float(hs1[nt]);
    }

    __syncthreads();   // staging complete (vmcnt0 drained at barrier)

    // ---- QK^T ----
    const bf16x8 aq0 = *(const bf16x8*)&Q0[w * 16 + fr][fq * 8];
    const bf16x8 aq1 = *(const bf16x8*)&Q1[w * 16 + fr][fq * 8];
#pragma unroll
    for (int nt = 0; nt < 16; ++nt) {
        const bf16x8 bk0 = *(const bf16x8*)&K0[nt * 16 + fr][fq * 8];
        const bf16x8 bk1 = *(const bf16x8*)&K1[nt * 16 + fr][fq * 8];
        acc[nt] = __builtin_amdgcn_mfma_f32_16x16x32_bf16(aq0, bk0, acc[nt], 0, 0, 0);
        acc[nt] = __builtin_amdgcn_mfma_f32_16x16x32_bf16(aq1, bk1, acc[nt], 0, 0, 0);
    }

    // ---- softmax in registers (HW exp2/rcp) ----
    float ri[4];
#pragma unroll
    for (int r = 0; r < 4; ++r) {
        float mx = acc[0][r];
#pragma unroll
        for (int nt = 1; nt < 16; ++nt) mx = fmaxf(mx, acc[nt][r]);
        mx = fmaxf(mx, __shfl_xor(mx, 1));
        mx = fmaxf(mx, __shfl_xor(mx, 2));
        mx = fmaxf(mx, __shfl_xor(mx, 4));
        mx = fmaxf(mx, __shfl_xor(mx, 8));
        float s = 0.0f;
#pragma unroll
        for (int nt = 0; nt < 16; ++nt) {
            const float e = fast_exp(acc[nt][r] - mx);
            acc[nt][r] = e;
            s += e;
        }
        s += __shfl_xor(s, 1);
        s += __shfl_xor(s, 2);
        s += __shfl_xor(s, 4);
        s += __shfl_xor(s, 8);
        ri[r] = __builtin_amdgcn_rcpf(s);
    }

    __syncthreads();   // all K/Q reads complete before P overwrites the region

#pragma unroll
    for (int nt = 0; nt < 16; ++nt)
#pragma unroll
        for (int r = 0; r < 4; ++r)
            Pb[w * 16 + fq * 4 + r][nt * 16 + fr] = f2bf(acc[nt][r] * ri[r]);

    // ---- PV ----
    f32x4 o[4] = {};
#pragma unroll
    for (int kt = 0; kt < 8; ++kt) {
        const bf16x8 ap = *(const bf16x8*)&Pb[w * 16 + fr][kt * 32 + fq * 8];
#pragma unroll
        for (int nt2 = 0; nt2 < 4; ++nt2) {
            const bf16x8 bv_ = *(const bf16x8*)&Vs[kt * 64 + nt2 * 16 + fr][fq * 8];
            o[nt2] = __builtin_amdgcn_mfma_f32_16x16x32_bf16(ap, bv_, o[nt2], 0, 0, 0);
        }
    }

#pragma unroll
    for (int nt2 = 0; nt2 < 4; ++nt2)
#pragma unroll
        for (int r = 0; r < 4; ++r)
            CTXb[(size_t)(b * Nv + qb + r) * Dv + h * 64 + nt2 * 16 + fr] =
                f2bf(o[nt2][r]);
}

// ---------------------------------------------------------------------------
extern "C" void kernel_launch(void* const* d_in, const int* in_sizes, int n_in,
                              void* d_out, int out_size, void* d_ws, size_t ws_size,
                              hipStream_t stream) {
    (void)in_sizes; (void)n_in; (void)out_size; (void)ws_size;

    const float* inq  = (const float*)d_in[0];
    const float* ink  = (const float*)d_in[1];
    const float* inv  = (const float*)d_in[2];
    const float* box  = (const float*)d_in[3];
    const int*   mask = (const int*)d_in[4];
    const float* Wq   = (const float*)d_in[5];
    const float* bq   = (const float*)d_in[6];
    const float* Wk   = (const float*)d_in[7];
    const float* bk   = (const float*)d_in[8];
    const float* Wv   = (const float*)d_in[9];
    const float* bv   = (const float*)d_in[10];
    const float* Wo   = (const float*)d_in[11];
    const float* bo   = (const float*)d_in[12];
    const float* WGw  = (const float*)d_in[13];
    const float* WGb  = (const float*)d_in[14];

    char* W = (char*)d_ws;
    const size_t MB = 1048576;
    unsigned short* Qb2  = (unsigned short*)(W + 0);        // 4 MB bf16, pre-scaled 1/8
    unsigned short* Kb2  = (unsigned short*)(W + 4 * MB);   // 4 MB bf16
    unsigned short* Vt2  = (unsigned short*)(W + 8 * MB);   // 4 MB bf16 [b][d][m]
    unsigned short* Wt   = (unsigned short*)(W + 12 * MB);  // 2 MB
    float*          bst  = (float*)(W + 14 * MB);           // 8 KB
    unsigned short* CTXb = (unsigned short*)(W + 15 * MB);  // 4 MB
    unsigned short* Ab   = (unsigned short*)(W + 20 * MB);  // 12 MB
    __half*         LB   = (__half*)(W + 32 * MB);          // 16.8 MB

    float* out = (float*)d_out;

    mega1_kernel<<<7424, 256, 0, stream>>>(
        box, mask, WGw, WGb, LB,
        inq, ink, inv, Ab,
        Wq, Wk, Wv, Wo, bq, bk, bv, bo, Wt, bst);

    qkv_gemm_kernel<<<dim3(8, 32, 3), 256, 0, stream>>>(Ab, Wt, bst, Qb2, Kb2, Vt2);

    attn3_kernel<<<dim3(4, 8, 16), 256, 0, stream>>>(Qb2, Kb2, Vt2, LB, CTXb);

    out_gemm_kernel<<<dim3(8, 64), 256, 0, stream>>>(CTXb, Wt + 3 * (Dv * Dv), bst + 3 * Dv, out);
}